// Round 5
// baseline (30997.607 us; speedup 1.0000x reference)
//
#include <hip/hip_runtime.h>
#include <stdint.h>

#define N_PTS   65536
#define DIM     512
#define K_CL    256
#define ITERS   25
#define KC_TILE 9        // Eigen kc=288 split (proven irrelevant to result; kept)

// ---------------- Threefry-2x32 (JAX-exact, 20 rounds) ----------------
__host__ __device__ static inline uint32_t rotl32(uint32_t x, int d) {
  return (x << d) | (x >> (32 - d));
}

__host__ __device__ static inline void tf2x32(uint32_t k0, uint32_t k1,
                                              uint32_t x0, uint32_t x1,
                                              uint32_t* o0, uint32_t* o1) {
  const uint32_t ks0 = k0, ks1 = k1, ks2 = k0 ^ k1 ^ 0x1BD11BDAu;
  uint32_t v0 = x0 + ks0, v1 = x1 + ks1;
#define TF_ROUND(R) { v0 += v1; v1 = rotl32(v1, R); v1 ^= v0; }
  TF_ROUND(13) TF_ROUND(15) TF_ROUND(26) TF_ROUND(6)
  v0 += ks1; v1 += ks2 + 1u;
  TF_ROUND(17) TF_ROUND(29) TF_ROUND(16) TF_ROUND(24)
  v0 += ks2; v1 += ks0 + 2u;
  TF_ROUND(13) TF_ROUND(15) TF_ROUND(26) TF_ROUND(6)
  v0 += ks0; v1 += ks1 + 3u;
  TF_ROUND(17) TF_ROUND(29) TF_ROUND(16) TF_ROUND(24)
  v0 += ks1; v1 += ks2 + 4u;
  TF_ROUND(13) TF_ROUND(15) TF_ROUND(26) TF_ROUND(6)
  v0 += ks2; v1 += ks0 + 5u;
#undef TF_ROUND
  *o0 = v0; *o1 = v1;
}

// Partitionable random_bits, bit_width=32:  bits[i] = y0 ^ y1 of
// hash(key, (0, i)).   [jax/_src/prng.py: `bits1 ^ bits2` for 8/16/32-bit]
__global__ void genbits_kernel(unsigned long long* __restrict__ keyarr,
                               uint32_t k0, uint32_t k1) {
  int i = blockIdx.x * 256 + threadIdx.x;
  uint32_t y0, y1;
  tf2x32(k0, k1, 0u, (uint32_t)i, &y0, &y1);
  uint32_t bits = y0 ^ y1;
  keyarr[i] = ((unsigned long long)bits << 32) | (uint32_t)i;
}

// Single-workgroup bitonic sort of 65536 u64 keys (ascending).
__global__ void bitonic_kernel(unsigned long long* __restrict__ d) {
  const int n = N_PTS;
  for (int k = 2; k <= n; k <<= 1) {
    for (int j = k >> 1; j > 0; j >>= 1) {
      __syncthreads();
      for (int t = threadIdx.x; t < n / 2; t += blockDim.x) {
        int low = t & (j - 1);
        int i   = ((t ^ low) << 1) | low;
        int ixj = i | j;
        bool up = ((i & k) == 0);
        unsigned long long a = d[i], b = d[ixj];
        if ((a > b) == up) { d[i] = b; d[ixj] = a; }
      }
    }
  }
}

__global__ void extract_low_kernel(const unsigned long long* __restrict__ s,
                                   uint32_t* __restrict__ out) {
  int i = blockIdx.x * 256 + threadIdx.x;
  out[i] = (uint32_t)(s[i] & 0xffffffffULL);
}

__global__ void init_centers_kernel(const unsigned long long* __restrict__ sorted2,
                                    const uint32_t* __restrict__ perm1,
                                    const float* __restrict__ x,
                                    float* __restrict__ ctr) {
  int k = blockIdx.x, d = threadIdx.x;
  uint32_t p   = (uint32_t)(sorted2[k] & 0xffffffffULL);
  uint32_t src = perm1[p];
  ctr[k * DIM + d] = x[(size_t)src * DIM + d];
}

// ---------------- k-means iteration kernels ----------------
__global__ void cnorm_kernel(const float* __restrict__ ctr, float* __restrict__ cnorm) {
#pragma clang fp contract(off)
  int k = blockIdx.x * 64 + threadIdx.x;     // 4 blocks x 64 thr = 256
  float s = 0.f;
  for (int j = 0; j < DIM; j++) {
    float v = ctr[k * DIM + j];
    float p = v * v;
    s = s + p;
  }
  cnorm[k] = s;
}

// argmin fold: NaN is minimal; first index wins ties (lexicographic).
__device__ static inline void argmin_pick(float ov, int ok, float& bv, int& bk) {
  bool no = __builtin_isnan(ov), nb = __builtin_isnan(bv);
  bool take;
  if (no != nb)      take = no;
  else if (no)       take = ok < bk;
  else               take = (ov < bv) || (ov == bv && ok < bk);
  if (take) { bv = ov; bk = ok; }
}

// Fused distance-GEMM + argmin. Block: 64 points x 256 clusters, 256 threads.
__launch_bounds__(256)
__global__ void assign_kernel(const float* __restrict__ x,
                              const float* __restrict__ ctr,
                              const float* __restrict__ cnorm,
                              int* __restrict__ assign) {
#pragma clang fp contract(off)
  __shared__ float xs[64][36];
  __shared__ float cs[256][36];
  const int t  = threadIdx.x;
  const int tm = t >> 4;     // 0..15
  const int tn = t & 15;     // 0..15
  const int m0 = blockIdx.x * 64;

  float accA[4][16], accB[4][16];
#pragma unroll
  for (int m = 0; m < 4; m++)
#pragma unroll
    for (int c = 0; c < 16; c++) { accA[m][c] = 0.f; accB[m][c] = 0.f; }

  auto do_tiles = [&](int t0, int t1, float (&acc)[4][16]) {
    for (int tile = t0; tile < t1; ++tile) {
      const int k0 = tile * 32;
      __syncthreads();
#pragma unroll
      for (int j = 0; j < 2; j++) {            // x tile: 64 rows x 32
        int idx = j * 256 + t;
        int r = idx >> 3, c4 = (idx & 7) << 2;
        float4 v = *reinterpret_cast<const float4*>(&x[(size_t)(m0 + r) * DIM + k0 + c4]);
        *reinterpret_cast<float4*>(&xs[r][c4]) = v;
      }
#pragma unroll
      for (int j = 0; j < 8; j++) {            // centers tile: 256 rows x 32
        int idx = j * 256 + t;
        int r = idx >> 3, c4 = (idx & 7) << 2;
        float4 v = *reinterpret_cast<const float4*>(&ctr[(size_t)r * DIM + k0 + c4]);
        *reinterpret_cast<float4*>(&cs[r][c4]) = v;
      }
      __syncthreads();
#pragma unroll
      for (int kk = 0; kk < 32; kk += 4) {
        float4 a[4], b[16];
#pragma unroll
        for (int m = 0; m < 4; m++)
          a[m] = *reinterpret_cast<float4*>(&xs[tm * 4 + m][kk]);
#pragma unroll
        for (int c = 0; c < 16; c++)
          b[c] = *reinterpret_cast<float4*>(&cs[c * 16 + tn][kk]);
#pragma unroll
        for (int m = 0; m < 4; m++)
#pragma unroll
          for (int c = 0; c < 16; c++) {
            float s = acc[m][c], p;
            p = a[m].x * b[c].x; s = s + p;    // strict k-order, mul then add
            p = a[m].y * b[c].y; s = s + p;
            p = a[m].z * b[c].z; s = s + p;
            p = a[m].w * b[c].w; s = s + p;
            acc[m][c] = s;
          }
      }
    }
  };
  do_tiles(0, KC_TILE, accA);       // k = 0..287
  do_tiles(KC_TILE, 16, accB);      // k = 288..511

#pragma unroll
  for (int m = 0; m < 4; m++) {
    float bv = __int_as_float(0x7f800000);   // +inf
    int bk = 0x7fffffff;
#pragma unroll
    for (int c = 0; c < 16; c++) {
      int kc = c * 16 + tn;
      float dot = accA[m][c] + accB[m][c];   // kc-block join
      float twodot = 2.0f * dot;
      float d2 = cnorm[kc] - twodot;
      argmin_pick(d2, kc, bv, bk);
    }
    for (int s = 1; s < 16; s <<= 1) {
      float ov = __shfl_xor(bv, s);
      int   ok = __shfl_xor(bk, s);
      argmin_pick(ov, ok, bv, bk);
    }
    if (tn == 0) assign[m0 + tm * 4 + m] = bk;
  }
}

// Counting sort stage 1: per-block histogram, cluster-major output.
__global__ void hist_kernel(const int* __restrict__ assign, int* __restrict__ blockHist) {
  __shared__ int h[K_CL];
  int b = blockIdx.x, t = threadIdx.x;
  h[t] = 0; __syncthreads();
  int k = assign[b * 256 + t];
  atomicAdd(&h[k], 1);
  __syncthreads();
  blockHist[t * 256 + b] = h[t];
}

// Stage 2: exclusive scan (cluster-major), cluster starts, counts.
__global__ void scan_kernel(int* __restrict__ blockHist,
                            int* __restrict__ clusterStart,
                            int* __restrict__ counts) {
  __shared__ int tot[K_CL];
  __shared__ int cs_s[K_CL];
  int k = threadIdx.x;
  int s = 0;
  for (int b = 0; b < 256; b++) {
    int v = blockHist[k * 256 + b];
    blockHist[k * 256 + b] = s;
    s += v;
  }
  tot[k] = s; counts[k] = s;
  __syncthreads();
  if (k == 0) {
    int run = 0;
    for (int kk = 0; kk < K_CL; kk++) { cs_s[kk] = run; run += tot[kk]; }
  }
  __syncthreads();
  int base = cs_s[k];
  clusterStart[k] = base;
  for (int b = 0; b < 256; b++) blockHist[k * 256 + b] += base;
}

// Stage 3: stable scatter of point indices into cluster-sorted order.
__global__ void scatter_kernel(const int* __restrict__ assign,
                               const int* __restrict__ blockHist,
                               int* __restrict__ sortedIdx) {
  __shared__ int la[256];
  int b = blockIdx.x, t = threadIdx.x;
  int n = b * 256 + t;
  int k = assign[n];
  la[t] = k; __syncthreads();
  int rank = 0;
  for (int u = 0; u < t; u++) rank += (la[u] == k) ? 1 : 0;
  sortedIdx[blockHist[k * 256 + b] + rank] = n;
}

// Stage 4: per-cluster strictly-sequential sum (ascending point index) + divide.
__global__ void segsum_kernel(const float* __restrict__ x,
                              const int* __restrict__ sortedIdx,
                              const int* __restrict__ clusterStart,
                              const int* __restrict__ counts,
                              float* __restrict__ out) {
#pragma clang fp contract(off)
  int k = blockIdx.x, d = threadIdx.x;
  int start = clusterStart[k], cnt = counts[k];
  float s = 0.f;
  for (int i = 0; i < cnt; i++) {
    int idx = sortedIdx[start + i];
    s = s + x[(size_t)idx * DIM + d];
  }
  out[k * DIM + d] = s / (float)cnt;  // cnt==0 -> NaN, matches ref
}

// ---------------- host ----------------
extern "C" void kernel_launch(void* const* d_in, const int* in_sizes, int n_in,
                              void* d_out, int out_size, void* d_ws, size_t ws_size,
                              hipStream_t stream) {
  const float* x = (const float*)d_in[0];
  float* out = (float*)d_out;

  char* p = (char*)d_ws;
  auto alloc = [&](size_t bytes) {
    char* r = p;
    p += (bytes + 255) & ~(size_t)255;
    return r;
  };
  unsigned long long* keyA = (unsigned long long*)alloc(N_PTS * 8);
  unsigned long long* keyB = (unsigned long long*)alloc(N_PTS * 8);
  uint32_t* perm1          = (uint32_t*)alloc(N_PTS * 4);
  int* assign              = (int*)alloc(N_PTS * 4);
  int* blockHist           = (int*)alloc(K_CL * 256 * 4);
  int* clusterStart        = (int*)alloc(K_CL * 4);
  int* counts              = (int*)alloc(K_CL * 4);
  int* sortedIdx           = (int*)alloc(N_PTS * 4);
  float* ctrA              = (float*)alloc(K_CL * DIM * 4);
  float* ctrB              = (float*)alloc(K_CL * DIM * 4);
  float* cnorm             = (float*)alloc(K_CL * 4);

  // Partitionable (foldlike) threefry split: split(key)[j] = hash(key,(0,j)).
  // key(1) = (0, 1); carried key = split[0], subkey = split[1].
  uint32_t k1a, k1b, s1a, s1b;
  tf2x32(0u, 1u, 0u, 0u, &k1a, &k1b);
  tf2x32(0u, 1u, 0u, 1u, &s1a, &s1b);
  uint32_t k2a, k2b, s2a, s2b;
  tf2x32(k1a, k1b, 0u, 0u, &k2a, &k2b);
  tf2x32(k1a, k1b, 0u, 1u, &s2a, &s2b);

  genbits_kernel<<<256, 256, 0, stream>>>(keyA, s1a, s1b);
  bitonic_kernel<<<1, 1024, 0, stream>>>(keyA);
  extract_low_kernel<<<256, 256, 0, stream>>>(keyA, perm1);
  genbits_kernel<<<256, 256, 0, stream>>>(keyB, s2a, s2b);
  bitonic_kernel<<<1, 1024, 0, stream>>>(keyB);
  init_centers_kernel<<<K_CL, DIM, 0, stream>>>(keyB, perm1, x, ctrA);

  float* cur = ctrA;
  for (int it = 0; it < ITERS; ++it) {
    float* next = (it == ITERS - 1) ? out : ((it & 1) ? ctrA : ctrB);
    cnorm_kernel<<<4, 64, 0, stream>>>(cur, cnorm);
    assign_kernel<<<N_PTS / 64, 256, 0, stream>>>(x, cur, cnorm, assign);
    hist_kernel<<<256, 256, 0, stream>>>(assign, blockHist);
    scan_kernel<<<1, 256, 0, stream>>>(blockHist, clusterStart, counts);
    scatter_kernel<<<256, 256, 0, stream>>>(assign, blockHist, sortedIdx);
    segsum_kernel<<<K_CL, DIM, 0, stream>>>(x, sortedIdx, clusterStart, counts, next);
    cur = next;
  }
}

// Round 6
// 11497.651 us; speedup vs baseline: 2.6960x; 2.6960x over previous
//
#include <hip/hip_runtime.h>
#include <stdint.h>

#define N_PTS   65536
#define DIM     512
#define K_CL    256
#define ITERS   25
#define NCH     8          // deterministic chunks per cluster in segsum

// ---------------- Threefry-2x32 (JAX-exact, 20 rounds) ----------------
__host__ __device__ static inline uint32_t rotl32(uint32_t x, int d) {
  return (x << d) | (x >> (32 - d));
}

__host__ __device__ static inline void tf2x32(uint32_t k0, uint32_t k1,
                                              uint32_t x0, uint32_t x1,
                                              uint32_t* o0, uint32_t* o1) {
  const uint32_t ks0 = k0, ks1 = k1, ks2 = k0 ^ k1 ^ 0x1BD11BDAu;
  uint32_t v0 = x0 + ks0, v1 = x1 + ks1;
#define TF_ROUND(R) { v0 += v1; v1 = rotl32(v1, R); v1 ^= v0; }
  TF_ROUND(13) TF_ROUND(15) TF_ROUND(26) TF_ROUND(6)
  v0 += ks1; v1 += ks2 + 1u;
  TF_ROUND(17) TF_ROUND(29) TF_ROUND(16) TF_ROUND(24)
  v0 += ks2; v1 += ks0 + 2u;
  TF_ROUND(13) TF_ROUND(15) TF_ROUND(26) TF_ROUND(6)
  v0 += ks0; v1 += ks1 + 3u;
  TF_ROUND(17) TF_ROUND(29) TF_ROUND(16) TF_ROUND(24)
  v0 += ks1; v1 += ks2 + 4u;
  TF_ROUND(13) TF_ROUND(15) TF_ROUND(26) TF_ROUND(6)
  v0 += ks2; v1 += ks0 + 5u;
#undef TF_ROUND
  *o0 = v0; *o1 = v1;
}

// Partitionable random_bits (32-bit): bits[i] = y0 ^ y1 of hash(key,(0,i)).
__global__ void genbits_kernel(unsigned long long* __restrict__ keyarr,
                               uint32_t k0, uint32_t k1) {
  int i = blockIdx.x * 256 + threadIdx.x;
  uint32_t y0, y1;
  tf2x32(k0, k1, 0u, (uint32_t)i, &y0, &y1);
  uint32_t bits = y0 ^ y1;
  keyarr[i] = ((unsigned long long)bits << 32) | (uint32_t)i;
}

// ---- Bitonic sort, identical comparison network, split across launches ----
// Global step for one (k, j), j >= 2048.
__global__ void bitonic_global_step(unsigned long long* __restrict__ d,
                                    int k, int j) {
  int t = blockIdx.x * 256 + threadIdx.x;   // 0..32767
  int low = t & (j - 1);
  int i   = ((t ^ low) << 1) | low;
  int ixj = i | j;
  bool up = ((i & k) == 0);
  unsigned long long a = d[i], b = d[ixj];
  if ((a > b) == up) { d[i] = b; d[ixj] = a; }
}

// All phases k=2..2048 within each 2048-aligned chunk (LDS-resident).
__global__ void bitonic_local_start(unsigned long long* __restrict__ d) {
  __shared__ unsigned long long s[2048];
  const int base = blockIdx.x * 2048;
  for (int u = threadIdx.x; u < 2048; u += 1024) s[u] = d[base + u];
  __syncthreads();
  for (int k = 2; k <= 2048; k <<= 1) {
    for (int j = k >> 1; j > 0; j >>= 1) {
      int t = threadIdx.x;                  // 0..1023
      int low = t & (j - 1);
      int il  = ((t ^ low) << 1) | low;
      int ixj = il | j;
      bool up = (((base + il) & k) == 0);
      unsigned long long a = s[il], b = s[ixj];
      if ((a > b) == up) { s[il] = b; s[ixj] = a; }
      __syncthreads();
    }
  }
  for (int u = threadIdx.x; u < 2048; u += 1024) d[base + u] = s[u];
}

// Finish phase k: j = 1024 down to 1 (chunk-local).
__global__ void bitonic_local(unsigned long long* __restrict__ d, int k) {
  __shared__ unsigned long long s[2048];
  const int base = blockIdx.x * 2048;
  for (int u = threadIdx.x; u < 2048; u += 1024) s[u] = d[base + u];
  __syncthreads();
  for (int j = 1024; j > 0; j >>= 1) {
    int t = threadIdx.x;
    int low = t & (j - 1);
    int il  = ((t ^ low) << 1) | low;
    int ixj = il | j;
    bool up = (((base + il) & k) == 0);
    unsigned long long a = s[il], b = s[ixj];
    if ((a > b) == up) { s[il] = b; s[ixj] = a; }
    __syncthreads();
  }
  for (int u = threadIdx.x; u < 2048; u += 1024) d[base + u] = s[u];
}

__global__ void extract_low_kernel(const unsigned long long* __restrict__ s,
                                   uint32_t* __restrict__ out) {
  int i = blockIdx.x * 256 + threadIdx.x;
  out[i] = (uint32_t)(s[i] & 0xffffffffULL);
}

__global__ void init_centers_kernel(const unsigned long long* __restrict__ sorted2,
                                    const uint32_t* __restrict__ perm1,
                                    const float* __restrict__ x,
                                    float* __restrict__ ctr) {
  int k = blockIdx.x, d = threadIdx.x;
  uint32_t p   = (uint32_t)(sorted2[k] & 0xffffffffULL);
  uint32_t src = perm1[p];
  ctr[k * DIM + d] = x[(size_t)src * DIM + d];
}

// ---------------- k-means iteration kernels ----------------
__global__ void cnorm_kernel(const float* __restrict__ ctr, float* __restrict__ cnorm) {
#pragma clang fp contract(off)
  int k = blockIdx.x * 64 + threadIdx.x;     // 4 blocks x 64 thr = 256
  float s = 0.f;
  for (int j = 0; j < DIM; j++) {
    float v = ctr[k * DIM + j];
    float p = v * v;
    s = s + p;
  }
  cnorm[k] = s;
}

// argmin fold: NaN is minimal; first index wins ties (lexicographic).
__device__ static inline void argmin_pick(float ov, int ok, float& bv, int& bk) {
  bool no = __builtin_isnan(ov), nb = __builtin_isnan(bv);
  bool take;
  if (no != nb)      take = no;
  else if (no)       take = ok < bk;
  else               take = (ov < bv) || (ov == bv && ok < bk);
  if (take) { bv = ov; bk = ok; }
}

// Fused distance-GEMM + argmin. Block: 64 points x 256 clusters, 256 threads.
// fmaf accumulation (rounding-robustness proven: rounds 3/4 bit-identical).
__launch_bounds__(256)
__global__ void assign_kernel(const float* __restrict__ x,
                              const float* __restrict__ ctr,
                              const float* __restrict__ cnorm,
                              int* __restrict__ assign) {
  __shared__ float xs[64][36];
  __shared__ float cs[256][36];
  const int t  = threadIdx.x;
  const int tm = t >> 4;     // 0..15
  const int tn = t & 15;     // 0..15
  const int m0 = blockIdx.x * 64;

  float acc[4][16];
#pragma unroll
  for (int m = 0; m < 4; m++)
#pragma unroll
    for (int c = 0; c < 16; c++) acc[m][c] = 0.f;

  for (int k0 = 0; k0 < DIM; k0 += 32) {
    __syncthreads();
#pragma unroll
    for (int j = 0; j < 2; j++) {            // x tile: 64 rows x 32
      int idx = j * 256 + t;
      int r = idx >> 3, c4 = (idx & 7) << 2;
      float4 v = *reinterpret_cast<const float4*>(&x[(size_t)(m0 + r) * DIM + k0 + c4]);
      *reinterpret_cast<float4*>(&xs[r][c4]) = v;
    }
#pragma unroll
    for (int j = 0; j < 8; j++) {            // centers tile: 256 rows x 32
      int idx = j * 256 + t;
      int r = idx >> 3, c4 = (idx & 7) << 2;
      float4 v = *reinterpret_cast<const float4*>(&ctr[(size_t)r * DIM + k0 + c4]);
      *reinterpret_cast<float4*>(&cs[r][c4]) = v;
    }
    __syncthreads();
#pragma unroll
    for (int kk = 0; kk < 32; kk += 4) {
      float4 a[4], b[16];
#pragma unroll
      for (int m = 0; m < 4; m++)
        a[m] = *reinterpret_cast<float4*>(&xs[tm * 4 + m][kk]);
#pragma unroll
      for (int c = 0; c < 16; c++)
        b[c] = *reinterpret_cast<float4*>(&cs[c * 16 + tn][kk]);
#pragma unroll
      for (int m = 0; m < 4; m++)
#pragma unroll
        for (int c = 0; c < 16; c++) {
          float s = acc[m][c];
          s = fmaf(a[m].x, b[c].x, s);
          s = fmaf(a[m].y, b[c].y, s);
          s = fmaf(a[m].z, b[c].z, s);
          s = fmaf(a[m].w, b[c].w, s);
          acc[m][c] = s;
        }
    }
  }

#pragma unroll
  for (int m = 0; m < 4; m++) {
    float bv = __int_as_float(0x7f800000);   // +inf
    int bk = 0x7fffffff;
#pragma unroll
    for (int c = 0; c < 16; c++) {
      int kc = c * 16 + tn;
      float d2 = cnorm[kc] - 2.0f * acc[m][c];
      argmin_pick(d2, kc, bv, bk);
    }
    for (int s = 1; s < 16; s <<= 1) {
      float ov = __shfl_xor(bv, s);
      int   ok = __shfl_xor(bk, s);
      argmin_pick(ov, ok, bv, bk);
    }
    if (tn == 0) assign[m0 + tm * 4 + m] = bk;
  }
}

// Counting sort stage 1: per-block histogram, BLOCK-major output (coalesced).
__global__ void hist_kernel(const int* __restrict__ assign, int* __restrict__ blockHist) {
  __shared__ int h[K_CL];
  int b = blockIdx.x, t = threadIdx.x;
  h[t] = 0; __syncthreads();
  int k = assign[b * 256 + t];
  atomicAdd(&h[k], 1);
  __syncthreads();
  blockHist[b * 256 + t] = h[t];
}

// Stage 2: exclusive scan over blocks per cluster (block-major layout).
__global__ void scan_kernel(int* __restrict__ blockHist,
                            int* __restrict__ clusterStart,
                            int* __restrict__ counts) {
  __shared__ int tot[K_CL];
  __shared__ int cs_s[K_CL];
  int k = threadIdx.x;
  int s = 0;
  for (int b = 0; b < 256; b++) {
    int v = blockHist[b * 256 + k];          // coalesced across threads
    blockHist[b * 256 + k] = s;
    s += v;
  }
  tot[k] = s; counts[k] = s;
  __syncthreads();
  if (k == 0) {
    int run = 0;
    for (int kk = 0; kk < K_CL; kk++) { cs_s[kk] = run; run += tot[kk]; }
  }
  __syncthreads();
  int base = cs_s[k];
  clusterStart[k] = base;
  for (int b = 0; b < 256; b++) blockHist[b * 256 + k] += base;
}

// Stage 3: stable scatter of point indices into cluster-sorted order.
__global__ void scatter_kernel(const int* __restrict__ assign,
                               const int* __restrict__ blockHist,
                               int* __restrict__ sortedIdx) {
  __shared__ int la[256];
  int b = blockIdx.x, t = threadIdx.x;
  int n = b * 256 + t;
  int k = assign[n];
  la[t] = k; __syncthreads();
  int rank = 0;
  for (int u = 0; u < t; u++) rank += (la[u] == k) ? 1 : 0;
  sortedIdx[blockHist[b * 256 + k] + rank] = n;
}

// Stage 4a: per-(cluster, chunk) partial sums. 256*NCH blocks x 512 threads.
// Fixed deterministic chunking: ch = ceil(cnt/NCH); ascending order in-chunk.
__global__ void segsum_part_kernel(const float* __restrict__ x,
                                   const int* __restrict__ sortedIdx,
                                   const int* __restrict__ clusterStart,
                                   const int* __restrict__ counts,
                                   float* __restrict__ part) {
#pragma clang fp contract(off)
  int k = blockIdx.x >> 3;       // cluster  (NCH == 8)
  int c = blockIdx.x & 7;        // chunk
  int d = threadIdx.x;
  int start = clusterStart[k], cnt = counts[k];
  int ch = (cnt + NCH - 1) / NCH;
  int b0 = c * ch;
  int b1 = b0 + ch; if (b1 > cnt) b1 = cnt;
  float s = 0.f;
  for (int i = b0; i < b1; i++) {
    int idx = sortedIdx[start + i];
    s = s + x[(size_t)idx * DIM + d];
  }
  part[((size_t)k * NCH + c) * DIM + d] = s;
}

// Stage 4b: combine chunks in fixed ascending order, divide.
__global__ void segsum_final_kernel(const float* __restrict__ part,
                                    const int* __restrict__ counts,
                                    float* __restrict__ out) {
#pragma clang fp contract(off)
  int k = blockIdx.x, d = threadIdx.x;
  float s = 0.f;
#pragma unroll
  for (int c = 0; c < NCH; c++)
    s = s + part[((size_t)k * NCH + c) * DIM + d];
  out[k * DIM + d] = s / (float)counts[k];   // cnt==0 -> NaN, matches ref
}

// ---------------- host ----------------
static inline void run_sort(unsigned long long* d, hipStream_t stream) {
  bitonic_local_start<<<32, 1024, 0, stream>>>(d);
  for (int k = 4096; k <= 65536; k <<= 1) {
    for (int j = k >> 1; j >= 2048; j >>= 1)
      bitonic_global_step<<<128, 256, 0, stream>>>(d, k, j);
    bitonic_local<<<32, 1024, 0, stream>>>(d, k);
  }
}

extern "C" void kernel_launch(void* const* d_in, const int* in_sizes, int n_in,
                              void* d_out, int out_size, void* d_ws, size_t ws_size,
                              hipStream_t stream) {
  const float* x = (const float*)d_in[0];
  float* out = (float*)d_out;

  char* p = (char*)d_ws;
  auto alloc = [&](size_t bytes) {
    char* r = p;
    p += (bytes + 255) & ~(size_t)255;
    return r;
  };
  unsigned long long* keyA = (unsigned long long*)alloc(N_PTS * 8);
  unsigned long long* keyB = (unsigned long long*)alloc(N_PTS * 8);
  uint32_t* perm1          = (uint32_t*)alloc(N_PTS * 4);
  int* assign              = (int*)alloc(N_PTS * 4);
  int* blockHist           = (int*)alloc(K_CL * 256 * 4);
  int* clusterStart        = (int*)alloc(K_CL * 4);
  int* counts              = (int*)alloc(K_CL * 4);
  int* sortedIdx           = (int*)alloc(N_PTS * 4);
  float* ctrA              = (float*)alloc(K_CL * DIM * 4);
  float* ctrB              = (float*)alloc(K_CL * DIM * 4);
  float* cnorm             = (float*)alloc(K_CL * 4);
  float* part              = (float*)alloc((size_t)K_CL * NCH * DIM * 4);

  // Partitionable (foldlike) threefry split: split(key)[j] = hash(key,(0,j)).
  uint32_t k1a, k1b, s1a, s1b;
  tf2x32(0u, 1u, 0u, 0u, &k1a, &k1b);
  tf2x32(0u, 1u, 0u, 1u, &s1a, &s1b);
  uint32_t k2a, k2b, s2a, s2b;
  tf2x32(k1a, k1b, 0u, 0u, &k2a, &k2b);
  tf2x32(k1a, k1b, 0u, 1u, &s2a, &s2b);

  genbits_kernel<<<256, 256, 0, stream>>>(keyA, s1a, s1b);
  run_sort(keyA, stream);
  extract_low_kernel<<<256, 256, 0, stream>>>(keyA, perm1);
  genbits_kernel<<<256, 256, 0, stream>>>(keyB, s2a, s2b);
  run_sort(keyB, stream);
  init_centers_kernel<<<K_CL, DIM, 0, stream>>>(keyB, perm1, x, ctrA);

  float* cur = ctrA;
  for (int it = 0; it < ITERS; ++it) {
    float* next = (it == ITERS - 1) ? out : ((it & 1) ? ctrA : ctrB);
    cnorm_kernel<<<4, 64, 0, stream>>>(cur, cnorm);
    assign_kernel<<<N_PTS / 64, 256, 0, stream>>>(x, cur, cnorm, assign);
    hist_kernel<<<256, 256, 0, stream>>>(assign, blockHist);
    scan_kernel<<<1, 256, 0, stream>>>(blockHist, clusterStart, counts);
    scatter_kernel<<<256, 256, 0, stream>>>(assign, blockHist, sortedIdx);
    segsum_part_kernel<<<K_CL * NCH, DIM, 0, stream>>>(x, sortedIdx, clusterStart,
                                                       counts, part);
    segsum_final_kernel<<<K_CL, DIM, 0, stream>>>(part, counts, next);
    cur = next;
  }
}

// Round 9
// 8495.566 us; speedup vs baseline: 3.6487x; 1.3534x over previous
//
#include <hip/hip_runtime.h>
#include <hip/hip_bf16.h>
#include <stdint.h>

#define N_PTS   65536
#define DIM     512
#define K_CL    256
#define ITERS   25
#define NCH     8          // deterministic chunks per cluster in segsum
#define BM      64         // points per block in assign
#define TAU     1e-3f      // ambiguity margin for exact recheck

typedef __attribute__((ext_vector_type(8))) short  bf16x8;   // 8 bf16 (4 VGPRs)
typedef __attribute__((ext_vector_type(4))) float  f32x4;

// ---------------- Threefry-2x32 (JAX-exact, 20 rounds) ----------------
__host__ __device__ static inline uint32_t rotl32(uint32_t x, int d) {
  return (x << d) | (x >> (32 - d));
}

__host__ __device__ static inline void tf2x32(uint32_t k0, uint32_t k1,
                                              uint32_t x0, uint32_t x1,
                                              uint32_t* o0, uint32_t* o1) {
  const uint32_t ks0 = k0, ks1 = k1, ks2 = k0 ^ k1 ^ 0x1BD11BDAu;
  uint32_t v0 = x0 + ks0, v1 = x1 + ks1;
#define TF_ROUND(R) { v0 += v1; v1 = rotl32(v1, R); v1 ^= v0; }
  TF_ROUND(13) TF_ROUND(15) TF_ROUND(26) TF_ROUND(6)
  v0 += ks1; v1 += ks2 + 1u;
  TF_ROUND(17) TF_ROUND(29) TF_ROUND(16) TF_ROUND(24)
  v0 += ks2; v1 += ks0 + 2u;
  TF_ROUND(13) TF_ROUND(15) TF_ROUND(26) TF_ROUND(6)
  v0 += ks0; v1 += ks1 + 3u;
  TF_ROUND(17) TF_ROUND(29) TF_ROUND(16) TF_ROUND(24)
  v0 += ks1; v1 += ks2 + 4u;
  TF_ROUND(13) TF_ROUND(15) TF_ROUND(26) TF_ROUND(6)
  v0 += ks2; v1 += ks0 + 5u;
#undef TF_ROUND
  *o0 = v0; *o1 = v1;
}

// Partitionable random_bits (32-bit): bits[i] = y0 ^ y1 of hash(key,(0,i)).
__global__ void genbits_kernel(unsigned long long* __restrict__ keyarr,
                               uint32_t k0, uint32_t k1) {
  int i = blockIdx.x * 256 + threadIdx.x;
  uint32_t y0, y1;
  tf2x32(k0, k1, 0u, (uint32_t)i, &y0, &y1);
  uint32_t bits = y0 ^ y1;
  keyarr[i] = ((unsigned long long)bits << 32) | (uint32_t)i;
}

// ---- Bitonic sort, identical comparison network, split across launches ----
__global__ void bitonic_global_step(unsigned long long* __restrict__ d,
                                    int k, int j) {
  int t = blockIdx.x * 256 + threadIdx.x;   // 0..32767
  int low = t & (j - 1);
  int i   = ((t ^ low) << 1) | low;
  int ixj = i | j;
  bool up = ((i & k) == 0);
  unsigned long long a = d[i], b = d[ixj];
  if ((a > b) == up) { d[i] = b; d[ixj] = a; }
}

__global__ void bitonic_local_start(unsigned long long* __restrict__ d) {
  __shared__ unsigned long long s[2048];
  const int base = blockIdx.x * 2048;
  for (int u = threadIdx.x; u < 2048; u += 1024) s[u] = d[base + u];
  __syncthreads();
  for (int k = 2; k <= 2048; k <<= 1) {
    for (int j = k >> 1; j > 0; j >>= 1) {
      int t = threadIdx.x;
      int low = t & (j - 1);
      int il  = ((t ^ low) << 1) | low;
      int ixj = il | j;
      bool up = (((base + il) & k) == 0);
      unsigned long long a = s[il], b = s[ixj];
      if ((a > b) == up) { s[il] = b; s[ixj] = a; }
      __syncthreads();
    }
  }
  for (int u = threadIdx.x; u < 2048; u += 1024) d[base + u] = s[u];
}

__global__ void bitonic_local(unsigned long long* __restrict__ d, int k) {
  __shared__ unsigned long long s[2048];
  const int base = blockIdx.x * 2048;
  for (int u = threadIdx.x; u < 2048; u += 1024) s[u] = d[base + u];
  __syncthreads();
  for (int j = 1024; j > 0; j >>= 1) {
    int t = threadIdx.x;
    int low = t & (j - 1);
    int il  = ((t ^ low) << 1) | low;
    int ixj = il | j;
    bool up = (((base + il) & k) == 0);
    unsigned long long a = s[il], b = s[ixj];
    if ((a > b) == up) { s[il] = b; s[ixj] = a; }
    __syncthreads();
  }
  for (int u = threadIdx.x; u < 2048; u += 1024) d[base + u] = s[u];
}

__global__ void extract_low_kernel(const unsigned long long* __restrict__ s,
                                   uint32_t* __restrict__ out) {
  int i = blockIdx.x * 256 + threadIdx.x;
  out[i] = (uint32_t)(s[i] & 0xffffffffULL);
}

__global__ void init_centers_kernel(const unsigned long long* __restrict__ sorted2,
                                    const uint32_t* __restrict__ perm1,
                                    const float* __restrict__ x,
                                    float* __restrict__ ctr) {
  int k = blockIdx.x, d = threadIdx.x;
  uint32_t p   = (uint32_t)(sorted2[k] & 0xffffffffULL);
  uint32_t src = perm1[p];
  ctr[k * DIM + d] = x[(size_t)src * DIM + d];
}

// ---------------- bf16 3-way split helpers ----------------
__device__ static inline ushort f2bf(float f) {
  __hip_bfloat16 b = __float2bfloat16(f);
  return *reinterpret_cast<ushort*>(&b);
}
__device__ static inline float bf2f(ushort u) {
  __hip_bfloat16 b = *reinterpret_cast<__hip_bfloat16*>(&u);
  return __bfloat162float(b);
}
__device__ static inline void split3(float v, ushort& h, ushort& m, ushort& l) {
#pragma clang fp contract(off)
  h = f2bf(v);
  float r1 = v - bf2f(h);
  m = f2bf(r1);
  float r2 = r1 - bf2f(m);
  l = f2bf(r2);
}

// Per-iter center split: ctr (fp32) -> ch/cm/cl (bf16), row-major [256][512].
__global__ void csplit_kernel(const float* __restrict__ ctr,
                              ushort* __restrict__ ch,
                              ushort* __restrict__ cm,
                              ushort* __restrict__ cl) {
  int i = blockIdx.x * 256 + threadIdx.x;    // 512 blocks
  ushort h, m, l;
  split3(ctr[i], h, m, l);
  ch[i] = h; cm[i] = m; cl[i] = l;
}

// ---------------- k-means iteration kernels ----------------
// Also zeroes the ambiguous-point counter for this iteration.
__global__ void cnorm_kernel(const float* __restrict__ ctr, float* __restrict__ cnorm,
                             int* __restrict__ ambigCount) {
#pragma clang fp contract(off)
  int k = blockIdx.x * 64 + threadIdx.x;     // 4 blocks x 64 thr = 256
  if (k == 0) *ambigCount = 0;
  float s = 0.f;
  for (int j = 0; j < DIM; j++) {
    float v = ctr[k * DIM + j];
    float p = v * v;
    s = s + p;
  }
  cnorm[k] = s;
}

// argmin fold: NaN is minimal; first index wins ties (lexicographic).
__device__ static inline void argmin_pick(float ov, int ok, float& bv, int& bk) {
  bool no = __builtin_isnan(ov), nb = __builtin_isnan(bv);
  bool take;
  if (no != nb)      take = no;
  else if (no)       take = ok < bk;
  else               take = (ov < bv) || (ov == bv && ok < bk);
  if (take) { bv = ov; bk = ok; }
}

// ---- (best, idx, second) triple machinery for margin tracking ----
__device__ static inline bool before3(float a, int ai, float b, int bi) {
  bool na = __builtin_isnan(a), nb = __builtin_isnan(b);
  if (na != nb) return na;
  if (na)       return ai < bi;
  return a < b || (a == b && ai < bi);
}
__device__ static inline float valmin3(float a, float b) {
  if (__builtin_isnan(a) || __builtin_isnan(b)) return __int_as_float(0x7fc00000);
  return fminf(a, b);
}
// merge other triple (ob,oi,os) into (b,i,s); os >= ob always.
__device__ static inline void merge3(float ob, int oi, float os,
                                     float& b, int& i, float& s) {
  if (before3(ob, oi, b, i)) { s = valmin3(b, os); b = ob; i = oi; }
  else                        s = valmin3(s, ob);
}

// MFMA distance-GEMM + argmin + margin.  Block: 64 points x 256 clusters, 4 waves.
// fp32 emulated via 3-way bf16 split, 6 products. Points whose top-2 margin
// is not safely above TAU are appended to ambigList for exact recheck.
__launch_bounds__(256, 2)
__global__ void assign_mfma_kernel(const float* __restrict__ x,
                                   const ushort* __restrict__ ch,
                                   const ushort* __restrict__ cm,
                                   const ushort* __restrict__ cl,
                                   const float* __restrict__ cnorm,
                                   int* __restrict__ assign,
                                   int* __restrict__ ambigCount,
                                   int* __restrict__ ambigList) {
  __shared__ ushort ah[64][40], am[64][40], al[64][40];   // A splits, padded
  __shared__ float  redv[4][64];
  __shared__ int    redi[4][64];
  __shared__ float  reds[4][64];

  const int t = threadIdx.x;
  const int w = t >> 6;            // wave 0..3
  const int lane = t & 63;
  const int m0 = blockIdx.x * BM;
  const int colbase = w * 64;
  const int l15 = lane & 15, l4 = lane >> 4;

  f32x4 acc[4][4];                 // [rowtile][coltile]
#pragma unroll
  for (int i = 0; i < 4; i++)
#pragma unroll
    for (int j = 0; j < 4; j++) acc[i][j] = (f32x4)(0.f);

  for (int k0 = 0; k0 < DIM; k0 += 32) {
    __syncthreads();
    // ---- stage A: 64 rows x 32 k fp32 -> split -> LDS ----
    {
      int r = t >> 2, ko = (t & 3) * 8;
      const float* src = &x[(size_t)(m0 + r) * DIM + k0 + ko];
      float4 v0 = *reinterpret_cast<const float4*>(src);
      float4 v1 = *reinterpret_cast<const float4*>(src + 4);
      float vv[8] = {v0.x, v0.y, v0.z, v0.w, v1.x, v1.y, v1.z, v1.w};
      ushort h8[8], m8[8], l8[8];
#pragma unroll
      for (int q = 0; q < 8; q++) split3(vv[q], h8[q], m8[q], l8[q]);
      bf16x8 vh, vm, vl;
#pragma unroll
      for (int q = 0; q < 8; q++) { vh[q] = (short)h8[q]; vm[q] = (short)m8[q]; vl[q] = (short)l8[q]; }
      *reinterpret_cast<bf16x8*>(&ah[r][ko]) = vh;
      *reinterpret_cast<bf16x8*>(&am[r][ko]) = vm;
      *reinterpret_cast<bf16x8*>(&al[r][ko]) = vl;
    }
    __syncthreads();

    // ---- B fragments straight from global (L2-resident) ----
    bf16x8 bh[4], bm_[4], bl[4];
    {
      size_t rowoff = (size_t)(colbase + l15) * DIM + k0 + l4 * 8;
#pragma unroll
      for (int j = 0; j < 4; j++) {
        size_t off = rowoff + (size_t)j * 16 * DIM;
        bh[j]  = *reinterpret_cast<const bf16x8*>(&ch[off]);
        bm_[j] = *reinterpret_cast<const bf16x8*>(&cm[off]);
        bl[j]  = *reinterpret_cast<const bf16x8*>(&cl[off]);
      }
    }
    // ---- A fragments from LDS + 6-product MFMA ----
#pragma unroll
    for (int i = 0; i < 4; i++) {
      int r = i * 16 + l15, ko = l4 * 8;
      bf16x8 fah = *reinterpret_cast<bf16x8*>(&ah[r][ko]);
      bf16x8 fam = *reinterpret_cast<bf16x8*>(&am[r][ko]);
      bf16x8 fal = *reinterpret_cast<bf16x8*>(&al[r][ko]);
#pragma unroll
      for (int j = 0; j < 4; j++) {
        acc[i][j] = __builtin_amdgcn_mfma_f32_16x16x32_bf16(fah, bh[j],  acc[i][j], 0, 0, 0);
        acc[i][j] = __builtin_amdgcn_mfma_f32_16x16x32_bf16(fah, bm_[j], acc[i][j], 0, 0, 0);
        acc[i][j] = __builtin_amdgcn_mfma_f32_16x16x32_bf16(fam, bh[j],  acc[i][j], 0, 0, 0);
        acc[i][j] = __builtin_amdgcn_mfma_f32_16x16x32_bf16(fah, bl[j],  acc[i][j], 0, 0, 0);
        acc[i][j] = __builtin_amdgcn_mfma_f32_16x16x32_bf16(fam, bm_[j], acc[i][j], 0, 0, 0);
        acc[i][j] = __builtin_amdgcn_mfma_f32_16x16x32_bf16(fal, bh[j],  acc[i][j], 0, 0, 0);
      }
    }
  }

  // ---- epilogue: d2 = cnorm - 2*dot; (best, idx, second) over 256 clusters ----
  {
#pragma clang fp contract(off)
    float cn[4];
#pragma unroll
    for (int j = 0; j < 4; j++) cn[j] = cnorm[colbase + j * 16 + l15];

#pragma unroll
    for (int i = 0; i < 4; i++) {
#pragma unroll
      for (int reg = 0; reg < 4; reg++) {
        float bb = __int_as_float(0x7f800000);  // +inf
        int   bi = 0x7fffffff;
        float bs = __int_as_float(0x7f800000);
#pragma unroll
        for (int j = 0; j < 4; j++) {
          int col = colbase + j * 16 + l15;
          float d2 = cn[j] - 2.0f * acc[i][j][reg];
          merge3(d2, col, __int_as_float(0x7f800000), bb, bi, bs);
        }
#pragma unroll
        for (int s = 1; s < 16; s <<= 1) {
          float ob = __shfl_xor(bb, s);
          int   oi = __shfl_xor(bi, s);
          float os = __shfl_xor(bs, s);
          merge3(ob, oi, os, bb, bi, bs);
        }
        if (l15 == 0) {
          int row = i * 16 + l4 * 4 + reg;
          redv[w][row] = bb; redi[w][row] = bi; reds[w][row] = bs;
        }
      }
    }
    __syncthreads();
    if (t < 64) {
      float bb = __int_as_float(0x7f800000);
      int   bi = 0x7fffffff;
      float bs = __int_as_float(0x7f800000);
#pragma unroll
      for (int w2 = 0; w2 < 4; w2++)
        merge3(redv[w2][t], redi[w2][t], reds[w2][t], bb, bi, bs);
      assign[m0 + t] = bi;
      float margin = bs - bb;
      if (!(margin > TAU)) {                 // NaN margin also flags
        int pos = atomicAdd(ambigCount, 1);
        if (pos < N_PTS) ambigList[pos] = m0 + t;
      }
    }
  }
}

// Exact recheck of ambiguous points with the r5 bit-exact scheme:
// mul+add strict ascending k, kc=288 two-fold join. 256 thr = 256 clusters.
__launch_bounds__(256)
__global__ void refine_kernel(const float* __restrict__ x,
                              const float* __restrict__ ctr,
                              const float* __restrict__ cnorm,
                              const int* __restrict__ ambigList,
                              const int* __restrict__ ambigCount,
                              int* __restrict__ assign) {
  __shared__ float xrow[DIM];
  __shared__ float cs[K_CL][33];
  __shared__ float rv[K_CL];
  __shared__ int   ri[K_CL];
  const int t = threadIdx.x;
  int cnt = *ambigCount; if (cnt > N_PTS) cnt = N_PTS;
  for (int a = blockIdx.x; a < cnt; a += gridDim.x) {
    int pt = ambigList[a];
    __syncthreads();
    for (int u = t; u < DIM; u += 256) xrow[u] = x[(size_t)pt * DIM + u];
    float accA = 0.f, accB = 0.f;
    for (int c = 0; c < 16; c++) {
      __syncthreads();
      for (int u = t; u < K_CL * 32; u += 256) {
        int k = u >> 5, j = u & 31;
        cs[k][j] = ctr[(size_t)k * DIM + c * 32 + j];
      }
      __syncthreads();
      {
#pragma clang fp contract(off)
        float s = (c < 9) ? accA : accB;
        for (int j = 0; j < 32; j++) {
          float pv = xrow[c * 32 + j] * cs[t][j];
          s = s + pv;
        }
        if (c < 9) accA = s; else accB = s;
      }
    }
    float d2;
    {
#pragma clang fp contract(off)
      float dot = accA + accB;
      float tw = 2.0f * dot;
      d2 = cnorm[t] - tw;
    }
    rv[t] = d2; ri[t] = t;
    __syncthreads();
    for (int st = 128; st >= 1; st >>= 1) {
      if (t < st) argmin_pick(rv[t + st], ri[t + st], rv[t], ri[t]);
      __syncthreads();
    }
    if (t == 0) assign[pt] = ri[0];
  }
}

// Counting sort stage 1: per-block histogram, BLOCK-major output (coalesced).
__global__ void hist_kernel(const int* __restrict__ assign, int* __restrict__ blockHist) {
  __shared__ int h[K_CL];
  int b = blockIdx.x, t = threadIdx.x;
  h[t] = 0; __syncthreads();
  int k = assign[b * 256 + t];
  atomicAdd(&h[k], 1);
  __syncthreads();
  blockHist[b * 256 + t] = h[t];
}

// Stage 2: exclusive scan over blocks per cluster (block-major layout).
__global__ void scan_kernel(int* __restrict__ blockHist,
                            int* __restrict__ clusterStart,
                            int* __restrict__ counts) {
  __shared__ int tot[K_CL];
  __shared__ int cs_s[K_CL];
  int k = threadIdx.x;
  int s = 0;
  for (int b = 0; b < 256; b++) {
    int v = blockHist[b * 256 + k];
    blockHist[b * 256 + k] = s;
    s += v;
  }
  tot[k] = s; counts[k] = s;
  __syncthreads();
  if (k == 0) {
    int run = 0;
    for (int kk = 0; kk < K_CL; kk++) { cs_s[kk] = run; run += tot[kk]; }
  }
  __syncthreads();
  int base = cs_s[k];
  clusterStart[k] = base;
  for (int b = 0; b < 256; b++) blockHist[b * 256 + k] += base;
}

// Stage 3: stable scatter of point indices into cluster-sorted order.
__global__ void scatter_kernel(const int* __restrict__ assign,
                               const int* __restrict__ blockHist,
                               int* __restrict__ sortedIdx) {
  __shared__ int la[256];
  int b = blockIdx.x, t = threadIdx.x;
  int n = b * 256 + t;
  int k = assign[n];
  la[t] = k; __syncthreads();
  int rank = 0;
  for (int u = 0; u < t; u++) rank += (la[u] == k) ? 1 : 0;
  sortedIdx[blockHist[b * 256 + k] + rank] = n;
}

// Stage 4a: per-(cluster, chunk) partial sums. 256*NCH blocks x 512 threads.
__global__ void segsum_part_kernel(const float* __restrict__ x,
                                   const int* __restrict__ sortedIdx,
                                   const int* __restrict__ clusterStart,
                                   const int* __restrict__ counts,
                                   float* __restrict__ part) {
#pragma clang fp contract(off)
  int k = blockIdx.x >> 3;       // cluster  (NCH == 8)
  int c = blockIdx.x & 7;        // chunk
  int d = threadIdx.x;
  int start = clusterStart[k], cnt = counts[k];
  int ch = (cnt + NCH - 1) / NCH;
  int b0 = c * ch;
  int b1 = b0 + ch; if (b1 > cnt) b1 = cnt;
  float s = 0.f;
  for (int i = b0; i < b1; i++) {
    int idx = sortedIdx[start + i];
    s = s + x[(size_t)idx * DIM + d];
  }
  part[((size_t)k * NCH + c) * DIM + d] = s;
}

// Stage 4b: combine chunks in fixed ascending order, divide.
__global__ void segsum_final_kernel(const float* __restrict__ part,
                                    const int* __restrict__ counts,
                                    float* __restrict__ out) {
#pragma clang fp contract(off)
  int k = blockIdx.x, d = threadIdx.x;
  float s = 0.f;
#pragma unroll
  for (int c = 0; c < NCH; c++)
    s = s + part[((size_t)k * NCH + c) * DIM + d];
  out[k * DIM + d] = s / (float)counts[k];   // cnt==0 -> NaN, matches ref
}

// ---------------- host ----------------
static inline void run_sort(unsigned long long* d, hipStream_t stream) {
  bitonic_local_start<<<32, 1024, 0, stream>>>(d);
  for (int k = 4096; k <= 65536; k <<= 1) {
    for (int j = k >> 1; j >= 2048; j >>= 1)
      bitonic_global_step<<<128, 256, 0, stream>>>(d, k, j);
    bitonic_local<<<32, 1024, 0, stream>>>(d, k);
  }
}

extern "C" void kernel_launch(void* const* d_in, const int* in_sizes, int n_in,
                              void* d_out, int out_size, void* d_ws, size_t ws_size,
                              hipStream_t stream) {
  const float* x = (const float*)d_in[0];
  float* out = (float*)d_out;

  char* p = (char*)d_ws;
  auto alloc = [&](size_t bytes) {
    char* r = p;
    p += (bytes + 255) & ~(size_t)255;
    return r;
  };
  unsigned long long* keyA = (unsigned long long*)alloc(N_PTS * 8);
  unsigned long long* keyB = (unsigned long long*)alloc(N_PTS * 8);
  uint32_t* perm1          = (uint32_t*)alloc(N_PTS * 4);
  int* assign              = (int*)alloc(N_PTS * 4);
  int* blockHist           = (int*)alloc(K_CL * 256 * 4);
  int* clusterStart        = (int*)alloc(K_CL * 4);
  int* counts              = (int*)alloc(K_CL * 4);
  int* sortedIdx           = (int*)alloc(N_PTS * 4);
  float* ctrA              = (float*)alloc(K_CL * DIM * 4);
  float* ctrB              = (float*)alloc(K_CL * DIM * 4);
  float* cnorm             = (float*)alloc(K_CL * 4);
  float* part              = (float*)alloc((size_t)K_CL * NCH * DIM * 4);
  ushort* ch               = (ushort*)alloc((size_t)K_CL * DIM * 2);
  ushort* cm               = (ushort*)alloc((size_t)K_CL * DIM * 2);
  ushort* cl               = (ushort*)alloc((size_t)K_CL * DIM * 2);
  int* ambigCount          = (int*)alloc(4);
  int* ambigList           = (int*)alloc(N_PTS * 4);

  // Partitionable (foldlike) threefry split: split(key)[j] = hash(key,(0,j)).
  uint32_t k1a, k1b, s1a, s1b;
  tf2x32(0u, 1u, 0u, 0u, &k1a, &k1b);
  tf2x32(0u, 1u, 0u, 1u, &s1a, &s1b);
  uint32_t k2a, k2b, s2a, s2b;
  tf2x32(k1a, k1b, 0u, 0u, &k2a, &k2b);
  tf2x32(k1a, k1b, 0u, 1u, &s2a, &s2b);

  genbits_kernel<<<256, 256, 0, stream>>>(keyA, s1a, s1b);
  run_sort(keyA, stream);
  extract_low_kernel<<<256, 256, 0, stream>>>(keyA, perm1);
  genbits_kernel<<<256, 256, 0, stream>>>(keyB, s2a, s2b);
  run_sort(keyB, stream);
  init_centers_kernel<<<K_CL, DIM, 0, stream>>>(keyB, perm1, x, ctrA);

  float* cur = ctrA;
  for (int it = 0; it < ITERS; ++it) {
    float* next = (it == ITERS - 1) ? out : ((it & 1) ? ctrA : ctrB);
    cnorm_kernel<<<4, 64, 0, stream>>>(cur, cnorm, ambigCount);
    csplit_kernel<<<K_CL * DIM / 256, 256, 0, stream>>>(cur, ch, cm, cl);
    assign_mfma_kernel<<<N_PTS / BM, 256, 0, stream>>>(x, ch, cm, cl, cnorm, assign,
                                                       ambigCount, ambigList);
    refine_kernel<<<256, 256, 0, stream>>>(x, cur, cnorm, ambigList, ambigCount, assign);
    hist_kernel<<<256, 256, 0, stream>>>(assign, blockHist);
    scan_kernel<<<1, 256, 0, stream>>>(blockHist, clusterStart, counts);
    scatter_kernel<<<256, 256, 0, stream>>>(assign, blockHist, sortedIdx);
    segsum_part_kernel<<<K_CL * NCH, DIM, 0, stream>>>(x, sortedIdx, clusterStart,
                                                       counts, part);
    segsum_final_kernel<<<K_CL, DIM, 0, stream>>>(part, counts, next);
    cur = next;
  }
}